// Round 7
// baseline (285.983 us; speedup 1.0000x reference)
//
#include <hip/hip_runtime.h>
#include <math.h>

// Problem constants: B=8, D=8 (channels), H=256, W=256, M=256
#define HWPIX 65536
#define NMATCH 256
#define THETA_LEN 169

// Transcendental-free GELU (R6, unchanged):
//   gelu = 0.5x + |x|·a·Q(a^2), a=min(|x|,3.75); 9-10 full-rate VALU ops, no trans.
__device__ __forceinline__ float gelu_fast(float x) {
    const float ax = fabsf(x);
    const float a  = fminf(ax, 3.75f);
    const float u  = a * a;
    float h = fmaf(u, 1.02997e-5f, -4.28057e-4f);
    h = fmaf(u, h, 7.05740e-3f);
    h = fmaf(u, h, -6.20045e-2f);
    h = fmaf(u, h, 3.973531e-1f);
    const float m = a * h;
    const float t = ax * m;
    return fmaf(x, 0.5f, t);
}

// 4 waves/EU min -> VGPR cap 128: enough to hold x[10][4] + pipelined loads
// (R6's 36-VGPR codegen was register-starved; occupancy is not the binding
// resource for an issue-bound kernel).
__global__ __launch_bounds__(256, 4) void dmh_kernel(
    const float* __restrict__ E,       // (8, 8, 256, 256)
    const float* __restrict__ theta,   // (256, 169)
    const float* __restrict__ centers, // (256, 2)
    const int*   __restrict__ bidx,    // (256,)
    float* __restrict__ out)           // (256, 256, 256)
{
    // 16 blocks per match; each block owns 4 tiles (4096 px), amortizing the
    // per-block theta s_loads + prologue 4x vs R6.
    const int m   = blockIdx.x >> 4;
    const int sbl = blockIdx.x & 15;

    const float* __restrict__ th = theta + m * THETA_LEN;
    const float cx = centers[2 * m];
    const float cy = centers[2 * m + 1];
    const int   b  = bidx[m];
    const float* __restrict__ Ebase = E + (size_t)b * (8 * HWPIX);
    float* __restrict__ obase = out + (size_t)m * HWPIX;

    for (int t = 0; t < 4; ++t) {
        const int tile = sbl * 4 + t;
        const int p0   = tile * 1024 + threadIdx.x * 4;
        const float* __restrict__ Eb = Ebase + p0;

        const int h = p0 >> 8;
        const int w = p0 & 255;   // multiple of 4 -> 4 pixels share h

        float x[10][4];
        #pragma unroll
        for (int c = 0; c < 8; ++c) {
            const float4 v = *(const float4*)(Eb + (size_t)c * HWPIX);
            x[c][0] = v.x; x[c][1] = v.y; x[c][2] = v.z; x[c][3] = v.w;
        }
        const float ry = (h + 0.5f) * (1.0f / 256.0f) - cy;
        #pragma unroll
        for (int j = 0; j < 4; ++j) {
            x[8][j] = (w + j + 0.5f) * (1.0f / 256.0f) - cx;
            x[9][j] = ry;
        }

        // Layer 0: 10 -> 8
        float y[8][4];
        #pragma unroll
        for (int o = 0; o < 8; ++o) {
            const float bias = th[80 + o];
            float a[4] = {bias, bias, bias, bias};
            #pragma unroll
            for (int i = 0; i < 10; ++i) {
                const float wv = th[o * 10 + i];   // SGPR operand
                #pragma unroll
                for (int j = 0; j < 4; ++j) a[j] = fmaf(wv, x[i][j], a[j]);
            }
            #pragma unroll
            for (int j = 0; j < 4; ++j) y[o][j] = gelu_fast(a[j]);
        }

        // Layer 1: 8 -> 8
        float z[8][4];
        #pragma unroll
        for (int o = 0; o < 8; ++o) {
            const float bias = th[152 + o];
            float a[4] = {bias, bias, bias, bias};
            #pragma unroll
            for (int i = 0; i < 8; ++i) {
                const float wv = th[88 + o * 8 + i];
                #pragma unroll
                for (int j = 0; j < 4; ++j) a[j] = fmaf(wv, y[i][j], a[j]);
            }
            #pragma unroll
            for (int j = 0; j < 4; ++j) z[o][j] = gelu_fast(a[j]);
        }

        // Layer 2: 8 -> 1
        const float b2 = th[168];
        float r[4] = {b2, b2, b2, b2};
        #pragma unroll
        for (int i = 0; i < 8; ++i) {
            const float wv = th[160 + i];
            #pragma unroll
            for (int j = 0; j < 4; ++j) r[j] = fmaf(wv, z[i][j], r[j]);
        }

        float4 o4;
        o4.x = r[0]; o4.y = r[1]; o4.z = r[2]; o4.w = r[3];
        *(float4*)(obase + p0) = o4;
    }
}

extern "C" void kernel_launch(void* const* d_in, const int* in_sizes, int n_in,
                              void* d_out, int out_size, void* d_ws, size_t ws_size,
                              hipStream_t stream) {
    const float* E       = (const float*)d_in[0];
    const float* theta   = (const float*)d_in[1];
    const float* centers = (const float*)d_in[2];
    const int*   bidx    = (const int*)d_in[3];
    float* out = (float*)d_out;

    dim3 grid(NMATCH * 16);  // 4096 blocks, 4096 px/block
    dim3 block(256);
    hipLaunchKernelGGL(dmh_kernel, grid, block, 0, stream, E, theta, centers, bidx, out);
}